// Round 13
// baseline (737.184 us; speedup 1.0000x reference)
//
#include <hip/hip_runtime.h>
#include <hip/hip_bf16.h>

#define T_STEPS 24
#define NSLOPE 0.2f
#define PITCH2 136   // h pitch in halves (272B = 17x16B): 16B-aligned rows -> ds_read_b128
#define LOG2E 1.4426950408889634f

typedef _Float16 half8 __attribute__((ext_vector_type(8)));
typedef _Float16 half2_t __attribute__((ext_vector_type(2)));
typedef float floatx4 __attribute__((ext_vector_type(4)));

#if __has_builtin(__builtin_amdgcn_exp2f)
#define EXP2(x) __builtin_amdgcn_exp2f(x)
#else
#define EXP2(x) exp2f(x)
#endif
#define RCP(x) __builtin_amdgcn_rcpf(x)

// scalar-only activation macro. inputs pre-scaled by log2e (i,f,o) / 2log2e (g);
// c kept scaled by 2log2e. A0..A3 = gates i,f,g,o of ONE channel.
#define ACT(A0,A1,A2,A3,CS,HP) {                                        \
    float i_ = RCP(1.f + EXP2(-(A0)));                                  \
    float f_ = RCP(1.f + EXP2(-(A1)));                                  \
    float gr = RCP(1.f + EXP2(-(A2)));                                  \
    float o_ = RCP(1.f + EXP2(-(A3)));                                  \
    float gs = fmaf(gr, 4.f*LOG2E, -2.f*LOG2E);                         \
    float cs = fmaf(f_, (CS), i_*gs);                                   \
    (CS) = cs;                                                          \
    float tc = fmaf(RCP(1.f + EXP2(-cs)), 2.f, -1.f);                   \
    (HP) = (_Float16)(o_*tc); }

#define MFMA16(A,B,C) __builtin_amdgcn_mfma_f32_16x16x32_f16((A),(B),(C),0,0,0)

// ---------------- prep: fp16 MFMA A-fragments, adjacent-channel gate packing ----------------
// A-frag lane layout (16x16x32): row16 = lane&15, k = (lane>>4)*8 + b.
// M-tile (w,m): row16 = cl*4 + g -> gate row = g*64 + 8w + 2*cl + m.
// => C-frag aA/aB (m=0/1) = gates of ADJACENT channels 8w+2grp, 8w+2grp+1 -> half2 store.
__global__ __launch_bounds__(256) void prep_kernel(
    const float* __restrict__ W_ih1, const float* __restrict__ W_hh1,
    const float* __restrict__ b_ih1, const float* __restrict__ b_hh1,
    const float* __restrict__ W_ih2, const float* __restrict__ W_hh2,
    const float* __restrict__ b_ih2, const float* __restrict__ b_hh2,
    const float* __restrict__ glw, const float* __restrict__ glew,
    const float* __restrict__ atte, const unsigned char* __restrict__ mask_bytes,
    _Float16* __restrict__ W1F, _Float16* __restrict__ W2F, _Float16* __restrict__ W3F,
    float* __restrict__ b2P, float* __restrict__ ke, int* __restrict__ flag)
{
    int tid = blockIdx.x*blockDim.x + threadIdx.x;
    int nth = gridDim.x*blockDim.x;
    // W1F: [w:8][m:2][kt:3][lane][b] — layer1, K = [h1(64) | x,1,pad30], prescaled
    for (int idx = tid; idx < 24576; idx += nth){
        int b = idx & 7;
        int lane = (idx >> 3) & 63;
        int t2 = idx >> 9;          // 0..47
        int kt = t2 % 3;
        int t3 = t2 / 3;            // 0..15
        int m = t3 & 1, w = t3 >> 1;
        int row16 = lane & 15;
        int g = row16 & 3, cl = row16 >> 2;
        int row = g*64 + 8*w + 2*cl + m;
        float sc = (g == 2) ? 2.f*LOG2E : LOG2E;
        int k = (lane>>4)*8 + b;
        float val;
        if (kt < 2){ val = W_hh1[row*64 + 32*kt + k]; }
        else { val = (k == 0) ? W_ih1[row] : (k == 1) ? (b_ih1[row]+b_hh1[row]) : 0.f; }
        W1F[idx] = (_Float16)(val * sc);
    }
    // W2F: [w:8][m:2][kt:4][lane][b] — layer2, K = [h1(64) | h2(64)], prescaled
    for (int idx = tid; idx < 32768; idx += nth){
        int b = idx & 7;
        int lane = (idx >> 3) & 63;
        int kt = (idx >> 9) & 3;
        int t3 = idx >> 11;         // 0..15
        int m = t3 & 1, w = t3 >> 1;
        int row16 = lane & 15;
        int g = row16 & 3, cl = row16 >> 2;
        int row = g*64 + 8*w + 2*cl + m;
        float sc = (g == 2) ? 2.f*LOG2E : LOG2E;
        int k = 32*kt + (lane>>4)*8 + b;
        W2F[idx] = (_Float16)(((k < 64) ? W_ih2[row*64 + k] : W_hh2[row*64 + (k-64)]) * sc);
    }
    // W3F: [w:4][kt:2][lane][b] — GAT projection (unscaled, used by waves 0-3)
    for (int idx = tid; idx < 4096; idx += nth){
        int b = idx & 7, t1 = idx >> 3; int lane = t1 & 63, t2 = t1 >> 6;
        int kt = t2 & 1, w = t2 >> 1;
        int row = 16*w + (lane & 15);
        W3F[idx] = (_Float16)glw[row*64 + 32*kt + (lane>>4)*8 + b];
    }
    // b2P: [w:8][m:2][lane][r:4] — layer2 bias, C-frag layout (gate r of ch 8w+2grp+m)
    for (int idx = tid; idx < 4096; idx += nth){
        int r = idx & 3;
        int lane = (idx >> 2) & 63;
        int m = (idx >> 8) & 1;
        int w = idx >> 9;           // 0..7
        int grp = lane >> 4;
        int row = r*64 + 8*w + 2*grp + m;
        float sc = (r == 2) ? 2.f*LOG2E : LOG2E;
        b2P[idx] = (b_ih2[row] + b_hh2[row]) * sc;
    }
    if (tid < 4){ float s = 0.f; for (int c = 0; c < 16; c++) s += atte[tid*16+c]*glew[tid*16+c]; ke[tid] = s; }
    if (tid == 0){ int nz = 0;
        for (int i = 0; i < 4096; i++){ if ((i&3) != 0 && mask_bytes[i] != 0) nz++; }
        *flag = (nz == 0) ? 1 : 0; }
}

// ---------------- CSR build: degree count ----------------
__global__ __launch_bounds__(256) void count_kernel(
    const int* __restrict__ ei, const void* __restrict__ maskp, const int* __restrict__ flag,
    int* __restrict__ deg, int E)
{
    int e = blockIdx.x*256 + threadIdx.x;
    if (e >= E) return;
    bool m = (*flag) ? (((const int*)maskp)[e] != 0) : (((const unsigned char*)maskp)[e] != 0);
    if (!m) return;
    atomicAdd(deg + ei[E + e], 1);
}

// ---------------- CSR build: single-block exclusive scan, int4 ----------------
__global__ __launch_bounds__(1024) void scan_kernel(
    const int* __restrict__ deg, int* __restrict__ offs, int* __restrict__ cursor, int nn)
{
    __shared__ int wsum[16];
    __shared__ int sbase;
    int lane = threadIdx.x & 63, wv = threadIdx.x >> 6;
    if (threadIdx.x == 0) sbase = 0;
    __syncthreads();
    for (int base = 0; base < nn; base += 4096){
        int i0 = base + (int)threadIdx.x*4;
        int4 v = make_int4(0,0,0,0);
        if (i0 + 3 < nn) v = *(const int4*)(deg + i0);
        else {
            if (i0   < nn) v.x = deg[i0];
            if (i0+1 < nn) v.y = deg[i0+1];
            if (i0+2 < nn) v.z = deg[i0+2];
            if (i0+3 < nn) v.w = deg[i0+3];
        }
        int s = v.x + v.y + v.z + v.w;
        int sc = s;
        #pragma unroll
        for (int o = 1; o < 64; o <<= 1){ int t = __shfl_up(sc, o); if (lane >= o) sc += t; }
        if (lane == 63) wsum[wv] = sc;
        __syncthreads();
        int wbase = 0, total = 0;
        #pragma unroll
        for (int k = 0; k < 16; k++){ int sk = wsum[k]; if (k < wv) wbase += sk; total += sk; }
        int excl = sbase + wbase + sc - s;
        if (i0 < nn){
            int e0 = excl, e1 = e0 + v.x, e2 = e1 + v.y, e3 = e2 + v.z;
            if (i0 + 3 < nn){
                *(int4*)(offs + i0)   = make_int4(e0,e1,e2,e3);
                *(int4*)(cursor + i0) = make_int4(e0,e1,e2,e3);
            } else {
                offs[i0] = e0; cursor[i0] = e0;
                if (i0+1 < nn){ offs[i0+1] = e1; cursor[i0+1] = e1; }
                if (i0+2 < nn){ offs[i0+2] = e2; cursor[i0+2] = e2; }
            }
        }
        __syncthreads();
        if (threadIdx.x == 0) sbase += total;
        __syncthreads();
    }
    if (threadIdx.x == 0) offs[nn] = sbase;
}

// ---------------- CSR build: scatter (src, edge_attr) records ----------------
__global__ __launch_bounds__(256) void scatter_kernel(
    const int* __restrict__ ei, const float* __restrict__ ea, const void* __restrict__ maskp,
    const int* __restrict__ flag, int* __restrict__ cursor, int2* __restrict__ rec, int E)
{
    int e = blockIdx.x*256 + threadIdx.x;
    if (e >= E) return;
    bool m = (*flag) ? (((const int*)maskp)[e] != 0) : (((const unsigned char*)maskp)[e] != 0);
    if (!m) return;
    int d = ei[E + e];
    int pos = atomicAdd(cursor + d, 1);
    rec[pos] = make_int2(ei[e], __float_as_int(ea[e]));
}

// ---------------- one LSTM time-step (8-wave / 64-node: 4 nt-tiles, 2 barriers) ----------------
__device__ __forceinline__ void lstm_step(
    const _Float16* RB, _Float16* WB, const _Float16* x_lds, int t,
    const half8 (&w1f)[2][3], const half8 (&w2f)[2][4], const floatx4 (&b2v)[2],
    float* c1s, float* c2s, int col, int grp, int wv)
{
    // ---- layer 1: reads RB.h1, writes WB.h1 ----
    #pragma unroll
    for (int nt = 0; nt < 4; nt++){
        int node = nt*16 + col;
        half8 bf0 = *(const half8*)&RB[node*PITCH2 + grp*8];
        half8 bf1 = *(const half8*)&RB[node*PITCH2 + 32 + grp*8];
        half8 xb;
        #pragma unroll
        for (int b = 0; b < 8; b++) xb[b] = (_Float16)0.f;
        _Float16 xv = x_lds[node*26 + t];
        if (grp == 0){ xb[0] = xv; xb[1] = (_Float16)1.0f; }
        floatx4 aA = {0,0,0,0}, aB = {0,0,0,0};
        aA = MFMA16(w1f[0][0], bf0, aA);  aB = MFMA16(w1f[1][0], bf0, aB);
        aA = MFMA16(w1f[0][1], bf1, aA);  aB = MFMA16(w1f[1][1], bf1, aB);
        aA = MFMA16(w1f[0][2], xb,  aA);  aB = MFMA16(w1f[1][2], xb,  aB);
        _Float16 hA, hB;
        ACT(aA[0], aA[1], aA[2], aA[3], c1s[nt*2+0], hA);
        ACT(aB[0], aB[1], aB[2], aB[3], c1s[nt*2+1], hB);
        half2_t hh; hh[0] = hA; hh[1] = hB;
        *(half2_t*)&WB[node*PITCH2 + 8*wv + 2*grp] = hh;   // channels 8w+2grp, +1
    }
    __syncthreads();
    // ---- layer 2: reads WB.h1 + RB.h2, writes WB.h2 ----
    #pragma unroll
    for (int nt = 0; nt < 4; nt++){
        int node = nt*16 + col;
        half8 bf0 = *(const half8*)&WB[node*PITCH2 + grp*8];
        half8 bf1 = *(const half8*)&WB[node*PITCH2 + 32 + grp*8];
        half8 bf2 = *(const half8*)&RB[node*PITCH2 + 64 + grp*8];
        half8 bf3 = *(const half8*)&RB[node*PITCH2 + 96 + grp*8];
        floatx4 aA = b2v[0], aB = b2v[1];
        aA = MFMA16(w2f[0][0], bf0, aA);  aB = MFMA16(w2f[1][0], bf0, aB);
        aA = MFMA16(w2f[0][1], bf1, aA);  aB = MFMA16(w2f[1][1], bf1, aB);
        aA = MFMA16(w2f[0][2], bf2, aA);  aB = MFMA16(w2f[1][2], bf2, aB);
        aA = MFMA16(w2f[0][3], bf3, aA);  aB = MFMA16(w2f[1][3], bf3, aB);
        _Float16 hA, hB;
        ACT(aA[0], aA[1], aA[2], aA[3], c2s[nt*2+0], hA);
        ACT(aB[0], aB[1], aB[2], aB[3], c2s[nt*2+1], hB);
        half2_t hh; hh[0] = hA; hh[1] = hB;
        *(half2_t*)&WB[node*PITCH2 + 64 + 8*wv + 2*grp] = hh;
    }
    __syncthreads();
}

// ---------------- fused MFMA LSTM + GAT projection + attention dots ----------------
// 8 waves x 64 nodes: barriers per node-step halved vs 32-node blocks; LDS 38.9KB ->
// 4 blocks/CU (155.6 <= 160KB), VGPR ~68 (no launch-bounds cap: R7/R8 lesson).
__global__ __launch_bounds__(512) void lstm_kernel(
    const float* __restrict__ x_in,
    const _Float16* __restrict__ W1F, const _Float16* __restrict__ W2F, const _Float16* __restrict__ W3F,
    const float* __restrict__ b2P,
    const float* __restrict__ atts, const float* __restrict__ attd,
    float* __restrict__ x_out, float* __restrict__ a_src, float* __restrict__ a_dst, int nn)
{
    __shared__ _Float16 hbuf0[64*PITCH2];
    __shared__ _Float16 hbuf1[64*PITCH2];
    __shared__ _Float16 x_lds[64*26];

    const int wv   = threadIdx.x >> 6;     // 0..7
    const int lane = threadIdx.x & 63;
    const int grp  = lane >> 4;
    const int col  = lane & 15;
    const int node0 = blockIdx.x * 64;

    for (int i = threadIdx.x; i < 64*T_STEPS; i += 512){
        int node = i / T_STEPS, t = i % T_STEPS;
        int nd = node0 + node;
        x_lds[node*26 + t] = (_Float16)((nd < nn) ? x_in[nd*T_STEPS + t] : 0.f);
    }
    for (int i = threadIdx.x; i < 64*PITCH2/2; i += 512) ((float*)hbuf0)[i] = 0.f;

    const half8* W1Fv = (const half8*)W1F;
    const half8* W2Fv = (const half8*)W2F;
    half8 w1f[2][3], w2f[2][4];
    floatx4 b2v[2];
    #pragma unroll
    for (int m = 0; m < 2; m++){
        #pragma unroll
        for (int kt = 0; kt < 3; kt++) w1f[m][kt] = W1Fv[((wv*2+m)*3+kt)*64 + lane];
        #pragma unroll
        for (int kt = 0; kt < 4; kt++) w2f[m][kt] = W2Fv[((wv*2+m)*4+kt)*64 + lane];
        b2v[m] = *(const floatx4*)&b2P[((wv*2+m)*64 + lane)*4];
    }

    float c1s[8], c2s[8];
    #pragma unroll
    for (int i = 0; i < 8; i++){ c1s[i] = 0.f; c2s[i] = 0.f; }

    __syncthreads();

    for (int t = 0; t < T_STEPS; t += 2){
        lstm_step(hbuf0, hbuf1, x_lds, t,   w1f, w2f, b2v, c1s, c2s, col, grp, wv);
        lstm_step(hbuf1, hbuf0, x_lds, t+1, w1f, w2f, b2v, c1s, c2s, col, grp, wv);
    }
    // final h2 in hbuf0

    // ---------- GAT projection + attention dots (waves 0-3 only; wave w = head w) ----------
    if (wv < 4){
        const half8* W3Fv = (const half8*)W3F;
        half8 w3f0 = W3Fv[(wv*2+0)*64 + lane];
        half8 w3f1 = W3Fv[(wv*2+1)*64 + lane];
        float asw[4], adw[4];
        #pragma unroll
        for (int r = 0; r < 4; r++){ int ch = 16*wv + grp*4 + r; asw[r] = atts[ch]; adw[r] = attd[ch]; }
        #pragma unroll
        for (int nt = 0; nt < 4; nt++){
            int node = nt*16 + col;
            int nd = node0 + node;
            floatx4 pa = {0,0,0,0};
            half8 bf0 = *(const half8*)&hbuf0[node*PITCH2 + 64 + grp*8];
            half8 bf1 = *(const half8*)&hbuf0[node*PITCH2 + 96 + grp*8];
            pa = MFMA16(w3f0, bf0, pa);
            pa = MFMA16(w3f1, bf1, pa);
            float s  = pa[0]*asw[0] + pa[1]*asw[1] + pa[2]*asw[2] + pa[3]*asw[3];
            float dv = pa[0]*adw[0] + pa[1]*adw[1] + pa[2]*adw[2] + pa[3]*adw[3];
            s  += __shfl_xor(s, 16);  s  += __shfl_xor(s, 32);
            dv += __shfl_xor(dv, 16); dv += __shfl_xor(dv, 32);
            if (nd < nn){
                *(float4*)(x_out + (size_t)nd*64 + 16*wv + grp*4) = make_float4(pa[0], pa[1], pa[2], pa[3]);
                if (grp == 0) a_src[nd*4 + wv] = s;
                else if (grp == 1) a_dst[nd*4 + wv] = dv;
            }
        }
    }
}

// ---------------- gather: wave-per-node CSR aggregation + fused finalize (4-way unroll) ----------------
__global__ __launch_bounds__(256) void gather_kernel(
    const int2* __restrict__ rec, const int* __restrict__ offs,
    const float* __restrict__ a_src, const float* __restrict__ a_dst, const float* __restrict__ ke,
    const float* __restrict__ xf, const float* __restrict__ gbias,
    const float* __restrict__ fcw, const float* __restrict__ fcb,
    float* __restrict__ y, int nn)
{
    int wv = threadIdx.x >> 6, lane = threadIdx.x & 63;
    int node = blockIdx.x*4 + wv;
    if (node >= nn) return;
    int h = lane >> 4;
    float keh = ke[h];
    float adv = a_dst[4*node + h];
    int beg = offs[node], end = offs[node+1];
    float acc = 0.f, dacc = 0.f;
    int j = beg;
    for (; j + 3 < end; j += 4){
        int2 r0 = rec[j], r1 = rec[j+1], r2 = rec[j+2], r3 = rec[j+3];
        int s0 = r0.x, s1 = r1.x, s2 = r2.x, s3 = r3.x;
        float as0 = a_src[4*s0 + h], as1 = a_src[4*s1 + h];
        float as2 = a_src[4*s2 + h], as3 = a_src[4*s3 + h];
        float x0 = xf[(size_t)s0*64 + lane], x1 = xf[(size_t)s1*64 + lane];
        float x2 = xf[(size_t)s2*64 + lane], x3 = xf[(size_t)s3*64 + lane];
        float a0 = as0 + adv + __int_as_float(r0.y)*keh;
        float a1 = as1 + adv + __int_as_float(r1.y)*keh;
        float a2 = as2 + adv + __int_as_float(r2.y)*keh;
        float a3 = as3 + adv + __int_as_float(r3.y)*keh;
        a0 = a0 > 0.f ? a0 : NSLOPE*a0;
        a1 = a1 > 0.f ? a1 : NSLOPE*a1;
        a2 = a2 > 0.f ? a2 : NSLOPE*a2;
        a3 = a3 > 0.f ? a3 : NSLOPE*a3;
        float e0 = __expf(a0), e1 = __expf(a1), e2 = __expf(a2), e3 = __expf(a3);
        dacc += (e0 + e1) + (e2 + e3);
        acc = fmaf(e0, x0, acc);
        acc = fmaf(e1, x1, acc);
        acc = fmaf(e2, x2, acc);
        acc = fmaf(e3, x3, acc);
    }
    for (; j < end; ++j){
        int2 r = rec[j];
        int s = r.x;
        float a = a_src[4*s + h] + adv + __int_as_float(r.y)*keh;
        a = a > 0.f ? a : NSLOPE*a;
        float ev = __expf(a);
        dacc += ev;
        acc = fmaf(ev, xf[(size_t)s*64 + lane], acc);
    }
    float v = acc * RCP(fmaxf(dacc, 1e-16f)) + gbias[lane];
    v = v > 0.f ? v : (__expf(v) - 1.f);
    float r2 = v * fcw[lane];
    #pragma unroll
    for (int off = 1; off < 64; off <<= 1) r2 += __shfl_xor(r2, off, 64);
    if (lane == 0) y[node] = r2 + fcb[0];
}

extern "C" void kernel_launch(void* const* d_in, const int* in_sizes, int n_in,
                              void* d_out, int out_size, void* d_ws, size_t ws_size,
                              hipStream_t stream)
{
    const float* x_in  = (const float*)d_in[0];
    const int*   ei    = (const int*)d_in[1];
    const float* ea    = (const float*)d_in[2];
    const void*  mask  = d_in[3];
    const float* W_ih1 = (const float*)d_in[4];
    const float* W_hh1 = (const float*)d_in[5];
    const float* b_ih1 = (const float*)d_in[6];
    const float* b_hh1 = (const float*)d_in[7];
    const float* W_ih2 = (const float*)d_in[8];
    const float* W_hh2 = (const float*)d_in[9];
    const float* b_ih2 = (const float*)d_in[10];
    const float* b_hh2 = (const float*)d_in[11];
    const float* glw   = (const float*)d_in[12];
    const float* glew  = (const float*)d_in[13];
    const float* atts  = (const float*)d_in[14];
    const float* attd  = (const float*)d_in[15];
    const float* atte  = (const float*)d_in[16];
    const float* gbias = (const float*)d_in[17];
    const float* fcw   = (const float*)d_in[18];
    const float* fcb   = (const float*)d_in[19];

    const int NN = in_sizes[0] / T_STEPS;
    const int E  = in_sizes[1] / 2;

    float* ws = (float*)d_ws;
    size_t o = 0;
    _Float16* W1F = (_Float16*)(ws + o); o += 24576/2;
    _Float16* W2F = (_Float16*)(ws + o); o += 32768/2;
    _Float16* W3F = (_Float16*)(ws + o); o += 4096/2;
    float* b2P = ws + o; o += 4096;
    float* ke  = ws + o; o += 64;
    int*  flag = (int*)(ws + o); o += 64;
    float* asrc= ws + o; o += (size_t)NN*4;
    float* adst= ws + o; o += (size_t)NN*4;
    float* xf  = ws + o; o += (size_t)NN*64;
    int* deg    = (int*)(ws + o); o += NN;
    int* offs   = (int*)(ws + o); o += NN + 64;
    int* cursor = (int*)(ws + o); o += NN;
    int2* rec   = (int2*)(ws + o); o += (size_t)E*2;

    hipMemsetAsync(deg, 0, (size_t)NN*sizeof(int), stream);

    prep_kernel<<<64, 256, 0, stream>>>(W_ih1, W_hh1, b_ih1, b_hh1, W_ih2, W_hh2, b_ih2, b_hh2,
                                        glw, glew, atte, (const unsigned char*)mask,
                                        W1F, W2F, W3F, b2P, ke, flag);
    count_kernel<<<(E + 255)/256, 256, 0, stream>>>(ei, mask, flag, deg, E);
    scan_kernel<<<1, 1024, 0, stream>>>(deg, offs, cursor, NN);
    scatter_kernel<<<(E + 255)/256, 256, 0, stream>>>(ei, ea, mask, flag, cursor, rec, E);
    lstm_kernel<<<(NN + 63)/64, 512, 0, stream>>>(x_in, W1F, W2F, W3F, b2P,
                                                  atts, attd, xf, asrc, adst, NN);
    gather_kernel<<<(NN + 3)/4, 256, 0, stream>>>(rec, offs, asrc, adst, ke, xf,
                                                  gbias, fcw, fcb, (float*)d_out, NN);
}

// Round 14
// 612.785 us; speedup vs baseline: 1.2030x; 1.2030x over previous
//
#include <hip/hip_runtime.h>
#include <hip/hip_bf16.h>

#define T_STEPS 24
#define NSLOPE 0.2f
#define PITCH2 136   // h pitch in halves (272B = 17x16B): 16B-aligned rows -> ds_read_b128
#define LOG2E 1.4426950408889634f

typedef _Float16 half8 __attribute__((ext_vector_type(8)));
typedef _Float16 half2_t __attribute__((ext_vector_type(2)));
typedef float floatx4 __attribute__((ext_vector_type(4)));

#if __has_builtin(__builtin_amdgcn_exp2f)
#define EXP2(x) __builtin_amdgcn_exp2f(x)
#else
#define EXP2(x) exp2f(x)
#endif
#define RCP(x) __builtin_amdgcn_rcpf(x)

// scalar-only activation macro. inputs pre-scaled by log2e (i,f,o) / 2log2e (g);
// c kept scaled by 2log2e. A0..A3 = gates i,f,g,o of ONE channel.
#define ACT(A0,A1,A2,A3,CS,HP) {                                        \
    float i_ = RCP(1.f + EXP2(-(A0)));                                  \
    float f_ = RCP(1.f + EXP2(-(A1)));                                  \
    float gr = RCP(1.f + EXP2(-(A2)));                                  \
    float o_ = RCP(1.f + EXP2(-(A3)));                                  \
    float gs = fmaf(gr, 4.f*LOG2E, -2.f*LOG2E);                         \
    float cs = fmaf(f_, (CS), i_*gs);                                   \
    (CS) = cs;                                                          \
    float tc = fmaf(RCP(1.f + EXP2(-cs)), 2.f, -1.f);                   \
    (HP) = (_Float16)(o_*tc); }

#define MFMA16(A,B,C) __builtin_amdgcn_mfma_f32_16x16x32_f16((A),(B),(C),0,0,0)

// ---------------- prep: fp16 MFMA A-fragments, adjacent-channel gate packing; zeros deg ----------------
// A-frag lane layout (16x16x32): row16 = lane&15, k = (lane>>4)*8 + b.
// M-tile (w,m): row16 = cl*4 + g -> gate row = g*64 + 8w + 2*cl + m.
// => C-frag aA/aB (m=0/1) = gates of ADJACENT channels 8w+2grp, 8w+2grp+1 -> half2 store.
__global__ __launch_bounds__(256) void prep_kernel(
    const float* __restrict__ W_ih1, const float* __restrict__ W_hh1,
    const float* __restrict__ b_ih1, const float* __restrict__ b_hh1,
    const float* __restrict__ W_ih2, const float* __restrict__ W_hh2,
    const float* __restrict__ b_ih2, const float* __restrict__ b_hh2,
    const float* __restrict__ glw, const float* __restrict__ glew,
    const float* __restrict__ atte, const unsigned char* __restrict__ mask_bytes,
    _Float16* __restrict__ W1F, _Float16* __restrict__ W2F, _Float16* __restrict__ W3F,
    float* __restrict__ b2P, float* __restrict__ ke, int* __restrict__ flag,
    int* __restrict__ deg, int nn)
{
    int tid = blockIdx.x*blockDim.x + threadIdx.x;
    int nth = gridDim.x*blockDim.x;
    // zero degree array (replaces hipMemsetAsync; count runs after prep on same stream)
    for (int i = tid; i < nn; i += nth) deg[i] = 0;
    // W1F: [w:8][m:2][kt:3][lane][b] — layer1, K = [h1(64) | x,1,pad30], prescaled
    for (int idx = tid; idx < 24576; idx += nth){
        int b = idx & 7;
        int lane = (idx >> 3) & 63;
        int t2 = idx >> 9;          // 0..47
        int kt = t2 % 3;
        int t3 = t2 / 3;            // 0..15
        int m = t3 & 1, w = t3 >> 1;
        int row16 = lane & 15;
        int g = row16 & 3, cl = row16 >> 2;
        int row = g*64 + 8*w + 2*cl + m;
        float sc = (g == 2) ? 2.f*LOG2E : LOG2E;
        int k = (lane>>4)*8 + b;
        float val;
        if (kt < 2){ val = W_hh1[row*64 + 32*kt + k]; }
        else { val = (k == 0) ? W_ih1[row] : (k == 1) ? (b_ih1[row]+b_hh1[row]) : 0.f; }
        W1F[idx] = (_Float16)(val * sc);
    }
    // W2F: [w:8][m:2][kt:4][lane][b] — layer2, K = [h1(64) | h2(64)], prescaled
    for (int idx = tid; idx < 32768; idx += nth){
        int b = idx & 7;
        int lane = (idx >> 3) & 63;
        int kt = (idx >> 9) & 3;
        int t3 = idx >> 11;         // 0..15
        int m = t3 & 1, w = t3 >> 1;
        int row16 = lane & 15;
        int g = row16 & 3, cl = row16 >> 2;
        int row = g*64 + 8*w + 2*cl + m;
        float sc = (g == 2) ? 2.f*LOG2E : LOG2E;
        int k = 32*kt + (lane>>4)*8 + b;
        W2F[idx] = (_Float16)(((k < 64) ? W_ih2[row*64 + k] : W_hh2[row*64 + (k-64)]) * sc);
    }
    // W3F: [w:4][kt:2][lane][b] — GAT projection (unscaled, used by waves 0-3)
    for (int idx = tid; idx < 4096; idx += nth){
        int b = idx & 7, t1 = idx >> 3; int lane = t1 & 63, t2 = t1 >> 6;
        int kt = t2 & 1, w = t2 >> 1;
        int row = 16*w + (lane & 15);
        W3F[idx] = (_Float16)glw[row*64 + 32*kt + (lane>>4)*8 + b];
    }
    // b2P: [w:8][m:2][lane][r:4] — layer2 bias, C-frag layout (gate r of ch 8w+2grp+m)
    for (int idx = tid; idx < 4096; idx += nth){
        int r = idx & 3;
        int lane = (idx >> 2) & 63;
        int m = (idx >> 8) & 1;
        int w = idx >> 9;           // 0..7
        int grp = lane >> 4;
        int row = r*64 + 8*w + 2*grp + m;
        float sc = (r == 2) ? 2.f*LOG2E : LOG2E;
        b2P[idx] = (b_ih2[row] + b_hh2[row]) * sc;
    }
    if (tid < 4){ float s = 0.f; for (int c = 0; c < 16; c++) s += atte[tid*16+c]*glew[tid*16+c]; ke[tid] = s; }
    if (tid == 0){ int nz = 0;
        for (int i = 0; i < 4096; i++){ if ((i&3) != 0 && mask_bytes[i] != 0) nz++; }
        *flag = (nz == 0) ? 1 : 0; }
}

// ---------------- CSR build: degree count ----------------
__global__ __launch_bounds__(256) void count_kernel(
    const int* __restrict__ ei, const void* __restrict__ maskp, const int* __restrict__ flag,
    int* __restrict__ deg, int E)
{
    int e = blockIdx.x*256 + threadIdx.x;
    if (e >= E) return;
    bool m = (*flag) ? (((const int*)maskp)[e] != 0) : (((const unsigned char*)maskp)[e] != 0);
    if (!m) return;
    atomicAdd(deg + ei[E + e], 1);
}

// ---------------- CSR build: single-block exclusive scan, int4 ----------------
__global__ __launch_bounds__(1024) void scan_kernel(
    const int* __restrict__ deg, int* __restrict__ offs, int* __restrict__ cursor, int nn)
{
    __shared__ int wsum[16];
    __shared__ int sbase;
    int lane = threadIdx.x & 63, wv = threadIdx.x >> 6;
    if (threadIdx.x == 0) sbase = 0;
    __syncthreads();
    for (int base = 0; base < nn; base += 4096){
        int i0 = base + (int)threadIdx.x*4;
        int4 v = make_int4(0,0,0,0);
        if (i0 + 3 < nn) v = *(const int4*)(deg + i0);
        else {
            if (i0   < nn) v.x = deg[i0];
            if (i0+1 < nn) v.y = deg[i0+1];
            if (i0+2 < nn) v.z = deg[i0+2];
            if (i0+3 < nn) v.w = deg[i0+3];
        }
        int s = v.x + v.y + v.z + v.w;
        int sc = s;
        #pragma unroll
        for (int o = 1; o < 64; o <<= 1){ int t = __shfl_up(sc, o); if (lane >= o) sc += t; }
        if (lane == 63) wsum[wv] = sc;
        __syncthreads();
        int wbase = 0, total = 0;
        #pragma unroll
        for (int k = 0; k < 16; k++){ int sk = wsum[k]; if (k < wv) wbase += sk; total += sk; }
        int excl = sbase + wbase + sc - s;
        if (i0 < nn){
            int e0 = excl, e1 = e0 + v.x, e2 = e1 + v.y, e3 = e2 + v.z;
            if (i0 + 3 < nn){
                *(int4*)(offs + i0)   = make_int4(e0,e1,e2,e3);
                *(int4*)(cursor + i0) = make_int4(e0,e1,e2,e3);
            } else {
                offs[i0] = e0; cursor[i0] = e0;
                if (i0+1 < nn){ offs[i0+1] = e1; cursor[i0+1] = e1; }
                if (i0+2 < nn){ offs[i0+2] = e2; cursor[i0+2] = e2; }
            }
        }
        __syncthreads();
        if (threadIdx.x == 0) sbase += total;
        __syncthreads();
    }
    if (threadIdx.x == 0) offs[nn] = sbase;
}

// ---------------- CSR build: scatter (src, edge_attr) records ----------------
__global__ __launch_bounds__(256) void scatter_kernel(
    const int* __restrict__ ei, const float* __restrict__ ea, const void* __restrict__ maskp,
    const int* __restrict__ flag, int* __restrict__ cursor, int2* __restrict__ rec, int E)
{
    int e = blockIdx.x*256 + threadIdx.x;
    if (e >= E) return;
    bool m = (*flag) ? (((const int*)maskp)[e] != 0) : (((const unsigned char*)maskp)[e] != 0);
    if (!m) return;
    int d = ei[E + e];
    int pos = atomicAdd(cursor + d, 1);
    rec[pos] = make_int2(ei[e], __float_as_int(ea[e]));
}

// ---------------- one LSTM time-step (8-wave / 32-node, half2 stores, 2 barriers) ----------------
__device__ __forceinline__ void lstm_step(
    const _Float16* RB, _Float16* WB, const _Float16* x_lds, int t,
    const half8 (&w1f)[2][3], const half8 (&w2f)[2][4], const floatx4 (&b2v)[2],
    float* c1s, float* c2s, int col, int grp, int wv)
{
    // ---- layer 1: reads RB.h1, writes WB.h1 ----
    #pragma unroll
    for (int nt = 0; nt < 2; nt++){
        int node = nt*16 + col;
        half8 bf0 = *(const half8*)&RB[node*PITCH2 + grp*8];
        half8 bf1 = *(const half8*)&RB[node*PITCH2 + 32 + grp*8];
        half8 xb;
        #pragma unroll
        for (int b = 0; b < 8; b++) xb[b] = (_Float16)0.f;
        _Float16 xv = x_lds[node*26 + t];
        if (grp == 0){ xb[0] = xv; xb[1] = (_Float16)1.0f; }
        floatx4 aA = {0,0,0,0}, aB = {0,0,0,0};
        aA = MFMA16(w1f[0][0], bf0, aA);  aB = MFMA16(w1f[1][0], bf0, aB);
        aA = MFMA16(w1f[0][1], bf1, aA);  aB = MFMA16(w1f[1][1], bf1, aB);
        aA = MFMA16(w1f[0][2], xb,  aA);  aB = MFMA16(w1f[1][2], xb,  aB);
        _Float16 hA, hB;
        ACT(aA[0], aA[1], aA[2], aA[3], c1s[nt*2+0], hA);
        ACT(aB[0], aB[1], aB[2], aB[3], c1s[nt*2+1], hB);
        half2_t hh; hh[0] = hA; hh[1] = hB;
        *(half2_t*)&WB[node*PITCH2 + 8*wv + 2*grp] = hh;   // channels 8w+2grp, +1
    }
    __syncthreads();
    // ---- layer 2: reads WB.h1 + RB.h2, writes WB.h2 ----
    #pragma unroll
    for (int nt = 0; nt < 2; nt++){
        int node = nt*16 + col;
        half8 bf0 = *(const half8*)&WB[node*PITCH2 + grp*8];
        half8 bf1 = *(const half8*)&WB[node*PITCH2 + 32 + grp*8];
        half8 bf2 = *(const half8*)&RB[node*PITCH2 + 64 + grp*8];
        half8 bf3 = *(const half8*)&RB[node*PITCH2 + 96 + grp*8];
        floatx4 aA = b2v[0], aB = b2v[1];
        aA = MFMA16(w2f[0][0], bf0, aA);  aB = MFMA16(w2f[1][0], bf0, aB);
        aA = MFMA16(w2f[0][1], bf1, aA);  aB = MFMA16(w2f[1][1], bf1, aB);
        aA = MFMA16(w2f[0][2], bf2, aA);  aB = MFMA16(w2f[1][2], bf2, aB);
        aA = MFMA16(w2f[0][3], bf3, aA);  aB = MFMA16(w2f[1][3], bf3, aB);
        _Float16 hA, hB;
        ACT(aA[0], aA[1], aA[2], aA[3], c2s[nt*2+0], hA);
        ACT(aB[0], aB[1], aB[2], aB[3], c2s[nt*2+1], hB);
        half2_t hh; hh[0] = hA; hh[1] = hB;
        *(half2_t*)&WB[node*PITCH2 + 64 + 8*wv + 2*grp] = hh;
    }
    __syncthreads();
}

// ---------------- fused MFMA LSTM + GAT projection + attention dots ----------------
// 8 waves x 32 nodes, VGPR 60 — PINNED under the 64-VGPR occupancy cliff
// (R13 lesson: +8 VGPR -> waves/SIMD halve -> +27% time). Do not add live state.
__global__ __launch_bounds__(512) void lstm_kernel(
    const float* __restrict__ x_in,
    const _Float16* __restrict__ W1F, const _Float16* __restrict__ W2F, const _Float16* __restrict__ W3F,
    const float* __restrict__ b2P,
    const float* __restrict__ atts, const float* __restrict__ attd,
    float* __restrict__ x_out, float* __restrict__ a_src, float* __restrict__ a_dst, int nn)
{
    __shared__ _Float16 hbuf0[32*PITCH2];
    __shared__ _Float16 hbuf1[32*PITCH2];
    __shared__ _Float16 x_lds[32*26];

    const int wv   = threadIdx.x >> 6;     // 0..7
    const int lane = threadIdx.x & 63;
    const int grp  = lane >> 4;
    const int col  = lane & 15;
    const int node0 = blockIdx.x * 32;

    for (int i = threadIdx.x; i < 32*T_STEPS; i += 512){
        int node = i / T_STEPS, t = i % T_STEPS;
        int nd = node0 + node;
        x_lds[node*26 + t] = (_Float16)((nd < nn) ? x_in[nd*T_STEPS + t] : 0.f);
    }
    for (int i = threadIdx.x; i < 32*PITCH2/2; i += 512) ((float*)hbuf0)[i] = 0.f;

    const half8* W1Fv = (const half8*)W1F;
    const half8* W2Fv = (const half8*)W2F;
    half8 w1f[2][3], w2f[2][4];
    floatx4 b2v[2];
    #pragma unroll
    for (int m = 0; m < 2; m++){
        #pragma unroll
        for (int kt = 0; kt < 3; kt++) w1f[m][kt] = W1Fv[((wv*2+m)*3+kt)*64 + lane];
        #pragma unroll
        for (int kt = 0; kt < 4; kt++) w2f[m][kt] = W2Fv[((wv*2+m)*4+kt)*64 + lane];
        b2v[m] = *(const floatx4*)&b2P[((wv*2+m)*64 + lane)*4];
    }

    float c1s[4], c2s[4];
    #pragma unroll
    for (int i = 0; i < 4; i++){ c1s[i] = 0.f; c2s[i] = 0.f; }

    __syncthreads();

    for (int t = 0; t < T_STEPS; t += 2){
        lstm_step(hbuf0, hbuf1, x_lds, t,   w1f, w2f, b2v, c1s, c2s, col, grp, wv);
        lstm_step(hbuf1, hbuf0, x_lds, t+1, w1f, w2f, b2v, c1s, c2s, col, grp, wv);
    }
    // final h2 in hbuf0

    // ---------- GAT projection + attention dots (waves 0-3 only; wave w = head w) ----------
    if (wv < 4){
        const half8* W3Fv = (const half8*)W3F;
        half8 w3f0 = W3Fv[(wv*2+0)*64 + lane];
        half8 w3f1 = W3Fv[(wv*2+1)*64 + lane];
        float asw[4], adw[4];
        #pragma unroll
        for (int r = 0; r < 4; r++){ int ch = 16*wv + grp*4 + r; asw[r] = atts[ch]; adw[r] = attd[ch]; }
        #pragma unroll
        for (int nt = 0; nt < 2; nt++){
            int node = nt*16 + col;
            int nd = node0 + node;
            floatx4 pa = {0,0,0,0};
            half8 bf0 = *(const half8*)&hbuf0[node*PITCH2 + 64 + grp*8];
            half8 bf1 = *(const half8*)&hbuf0[node*PITCH2 + 96 + grp*8];
            pa = MFMA16(w3f0, bf0, pa);
            pa = MFMA16(w3f1, bf1, pa);
            float s  = pa[0]*asw[0] + pa[1]*asw[1] + pa[2]*asw[2] + pa[3]*asw[3];
            float dv = pa[0]*adw[0] + pa[1]*adw[1] + pa[2]*adw[2] + pa[3]*adw[3];
            s  += __shfl_xor(s, 16);  s  += __shfl_xor(s, 32);
            dv += __shfl_xor(dv, 16); dv += __shfl_xor(dv, 32);
            if (nd < nn){
                *(float4*)(x_out + (size_t)nd*64 + 16*wv + grp*4) = make_float4(pa[0], pa[1], pa[2], pa[3]);
                if (grp == 0) a_src[nd*4 + wv] = s;
                else if (grp == 1) a_dst[nd*4 + wv] = dv;
            }
        }
    }
}

// ---------------- gather: wave-per-node CSR aggregation + fused finalize (4-way unroll) ----------------
__global__ __launch_bounds__(256) void gather_kernel(
    const int2* __restrict__ rec, const int* __restrict__ offs,
    const float* __restrict__ a_src, const float* __restrict__ a_dst, const float* __restrict__ ke,
    const float* __restrict__ xf, const float* __restrict__ gbias,
    const float* __restrict__ fcw, const float* __restrict__ fcb,
    float* __restrict__ y, int nn)
{
    int wv = threadIdx.x >> 6, lane = threadIdx.x & 63;
    int node = blockIdx.x*4 + wv;
    if (node >= nn) return;
    int h = lane >> 4;
    float keh = ke[h];
    float adv = a_dst[4*node + h];
    int beg = offs[node], end = offs[node+1];
    float acc = 0.f, dacc = 0.f;
    int j = beg;
    for (; j + 3 < end; j += 4){
        int2 r0 = rec[j], r1 = rec[j+1], r2 = rec[j+2], r3 = rec[j+3];
        int s0 = r0.x, s1 = r1.x, s2 = r2.x, s3 = r3.x;
        float as0 = a_src[4*s0 + h], as1 = a_src[4*s1 + h];
        float as2 = a_src[4*s2 + h], as3 = a_src[4*s3 + h];
        float x0 = xf[(size_t)s0*64 + lane], x1 = xf[(size_t)s1*64 + lane];
        float x2 = xf[(size_t)s2*64 + lane], x3 = xf[(size_t)s3*64 + lane];
        float a0 = as0 + adv + __int_as_float(r0.y)*keh;
        float a1 = as1 + adv + __int_as_float(r1.y)*keh;
        float a2 = as2 + adv + __int_as_float(r2.y)*keh;
        float a3 = as3 + adv + __int_as_float(r3.y)*keh;
        a0 = a0 > 0.f ? a0 : NSLOPE*a0;
        a1 = a1 > 0.f ? a1 : NSLOPE*a1;
        a2 = a2 > 0.f ? a2 : NSLOPE*a2;
        a3 = a3 > 0.f ? a3 : NSLOPE*a3;
        float e0 = __expf(a0), e1 = __expf(a1), e2 = __expf(a2), e3 = __expf(a3);
        dacc += (e0 + e1) + (e2 + e3);
        acc = fmaf(e0, x0, acc);
        acc = fmaf(e1, x1, acc);
        acc = fmaf(e2, x2, acc);
        acc = fmaf(e3, x3, acc);
    }
    for (; j < end; ++j){
        int2 r = rec[j];
        int s = r.x;
        float a = a_src[4*s + h] + adv + __int_as_float(r.y)*keh;
        a = a > 0.f ? a : NSLOPE*a;
        float ev = __expf(a);
        dacc += ev;
        acc = fmaf(ev, xf[(size_t)s*64 + lane], acc);
    }
    float v = acc * RCP(fmaxf(dacc, 1e-16f)) + gbias[lane];
    v = v > 0.f ? v : (__expf(v) - 1.f);
    float r2 = v * fcw[lane];
    #pragma unroll
    for (int off = 1; off < 64; off <<= 1) r2 += __shfl_xor(r2, off, 64);
    if (lane == 0) y[node] = r2 + fcb[0];
}

extern "C" void kernel_launch(void* const* d_in, const int* in_sizes, int n_in,
                              void* d_out, int out_size, void* d_ws, size_t ws_size,
                              hipStream_t stream)
{
    const float* x_in  = (const float*)d_in[0];
    const int*   ei    = (const int*)d_in[1];
    const float* ea    = (const float*)d_in[2];
    const void*  mask  = d_in[3];
    const float* W_ih1 = (const float*)d_in[4];
    const float* W_hh1 = (const float*)d_in[5];
    const float* b_ih1 = (const float*)d_in[6];
    const float* b_hh1 = (const float*)d_in[7];
    const float* W_ih2 = (const float*)d_in[8];
    const float* W_hh2 = (const float*)d_in[9];
    const float* b_ih2 = (const float*)d_in[10];
    const float* b_hh2 = (const float*)d_in[11];
    const float* glw   = (const float*)d_in[12];
    const float* glew  = (const float*)d_in[13];
    const float* atts  = (const float*)d_in[14];
    const float* attd  = (const float*)d_in[15];
    const float* atte  = (const float*)d_in[16];
    const float* gbias = (const float*)d_in[17];
    const float* fcw   = (const float*)d_in[18];
    const float* fcb   = (const float*)d_in[19];

    const int NN = in_sizes[0] / T_STEPS;
    const int E  = in_sizes[1] / 2;

    float* ws = (float*)d_ws;
    size_t o = 0;
    _Float16* W1F = (_Float16*)(ws + o); o += 24576/2;
    _Float16* W2F = (_Float16*)(ws + o); o += 32768/2;
    _Float16* W3F = (_Float16*)(ws + o); o += 4096/2;
    float* b2P = ws + o; o += 4096;
    float* ke  = ws + o; o += 64;
    int*  flag = (int*)(ws + o); o += 64;
    float* asrc= ws + o; o += (size_t)NN*4;
    float* adst= ws + o; o += (size_t)NN*4;
    float* xf  = ws + o; o += (size_t)NN*64;
    int* deg    = (int*)(ws + o); o += NN;
    int* offs   = (int*)(ws + o); o += NN + 64;
    int* cursor = (int*)(ws + o); o += NN;
    int2* rec   = (int2*)(ws + o); o += (size_t)E*2;

    prep_kernel<<<128, 256, 0, stream>>>(W_ih1, W_hh1, b_ih1, b_hh1, W_ih2, W_hh2, b_ih2, b_hh2,
                                         glw, glew, atte, (const unsigned char*)mask,
                                         W1F, W2F, W3F, b2P, ke, flag, deg, NN);
    count_kernel<<<(E + 255)/256, 256, 0, stream>>>(ei, mask, flag, deg, E);
    scan_kernel<<<1, 1024, 0, stream>>>(deg, offs, cursor, NN);
    scatter_kernel<<<(E + 255)/256, 256, 0, stream>>>(ei, ea, mask, flag, cursor, rec, E);
    lstm_kernel<<<(NN + 31)/32, 512, 0, stream>>>(x_in, W1F, W2F, W3F, b2P,
                                                  atts, attd, xf, asrc, adst, NN);
    gather_kernel<<<(NN + 3)/4, 256, 0, stream>>>(rec, offs, asrc, adst, ke, xf,
                                                  gbias, fcw, fcb, (float*)d_out, NN);
}

// Round 15
// 605.229 us; speedup vs baseline: 1.2180x; 1.0125x over previous
//
#include <hip/hip_runtime.h>
#include <hip/hip_bf16.h>

#define T_STEPS 24
#define NSLOPE 0.2f
#define PITCH2 136   // h pitch in halves (272B = 17x16B): 16B-aligned rows -> ds_read_b128
#define LOG2E 1.4426950408889634f

typedef _Float16 half8 __attribute__((ext_vector_type(8)));
typedef _Float16 half2_t __attribute__((ext_vector_type(2)));
typedef float floatx4 __attribute__((ext_vector_type(4)));

#if __has_builtin(__builtin_amdgcn_exp2f)
#define EXP2(x) __builtin_amdgcn_exp2f(x)
#else
#define EXP2(x) exp2f(x)
#endif
#define RCP(x) __builtin_amdgcn_rcpf(x)

// activation, trans-minimized: 5 exp2 + 3 rcp (was 5+5).
// identities: sigm(a)*tanh(b) via (1-v)*rcp((1+u)(1+v)); f-gate rcp kept separate.
// inputs pre-scaled by log2e (i,f,o) / 2log2e (g); c kept scaled by 2log2e.
#define ACT(A0,A1,A2,A3,CS,HP) {                                        \
    float u_ = EXP2(-(A0));                                             \
    float fw = EXP2(-(A1));                                             \
    float v_ = EXP2(-(A2));                                             \
    float xo = EXP2(-(A3));                                             \
    float f_ = RCP(1.f + fw);                                           \
    float ig = (1.f - v_) * RCP((1.f + u_) * (1.f + v_));               \
    float cs = fmaf(f_, (CS), ig * (2.f*LOG2E));                        \
    (CS) = cs;                                                          \
    float z_ = EXP2(-cs);                                               \
    (HP) = (_Float16)((1.f - z_) * RCP((1.f + xo) * (1.f + z_)));       \
}

#define MFMA16(A,B,C) __builtin_amdgcn_mfma_f32_16x16x32_f16((A),(B),(C),0,0,0)

// ---------------- prep: fp16 MFMA A-fragments, adjacent-channel gate packing; zeros deg ----------------
// A-frag lane layout (16x16x32): row16 = lane&15, k = (lane>>4)*8 + b.
// M-tile (w,m): row16 = cl*4 + g -> gate row = g*64 + 8w + 2*cl + m.
// => C-frag aA/aB (m=0/1) = gates of ADJACENT channels 8w+2grp, 8w+2grp+1 -> half2 store.
__global__ __launch_bounds__(256) void prep_kernel(
    const float* __restrict__ W_ih1, const float* __restrict__ W_hh1,
    const float* __restrict__ b_ih1, const float* __restrict__ b_hh1,
    const float* __restrict__ W_ih2, const float* __restrict__ W_hh2,
    const float* __restrict__ b_ih2, const float* __restrict__ b_hh2,
    const float* __restrict__ glw, const float* __restrict__ glew,
    const float* __restrict__ atte, const unsigned char* __restrict__ mask_bytes,
    _Float16* __restrict__ W1F, _Float16* __restrict__ W2F, _Float16* __restrict__ W3F,
    float* __restrict__ b2P, float* __restrict__ ke, int* __restrict__ flag,
    int* __restrict__ deg, int nn)
{
    int tid = blockIdx.x*blockDim.x + threadIdx.x;
    int nth = gridDim.x*blockDim.x;
    // zero degree array (replaces hipMemsetAsync; count runs after prep on same stream)
    for (int i = tid; i < nn; i += nth) deg[i] = 0;
    // W1F: [w:8][m:2][kt:3][lane][b] — layer1, K = [h1(64) | x,1,pad30], prescaled
    for (int idx = tid; idx < 24576; idx += nth){
        int b = idx & 7;
        int lane = (idx >> 3) & 63;
        int t2 = idx >> 9;          // 0..47
        int kt = t2 % 3;
        int t3 = t2 / 3;            // 0..15
        int m = t3 & 1, w = t3 >> 1;
        int row16 = lane & 15;
        int g = row16 & 3, cl = row16 >> 2;
        int row = g*64 + 8*w + 2*cl + m;
        float sc = (g == 2) ? 2.f*LOG2E : LOG2E;
        int k = (lane>>4)*8 + b;
        float val;
        if (kt < 2){ val = W_hh1[row*64 + 32*kt + k]; }
        else { val = (k == 0) ? W_ih1[row] : (k == 1) ? (b_ih1[row]+b_hh1[row]) : 0.f; }
        W1F[idx] = (_Float16)(val * sc);
    }
    // W2F: [w:8][m:2][kt:4][lane][b] — layer2, K = [h1(64) | h2(64)], prescaled
    for (int idx = tid; idx < 32768; idx += nth){
        int b = idx & 7;
        int lane = (idx >> 3) & 63;
        int kt = (idx >> 9) & 3;
        int t3 = idx >> 11;         // 0..15
        int m = t3 & 1, w = t3 >> 1;
        int row16 = lane & 15;
        int g = row16 & 3, cl = row16 >> 2;
        int row = g*64 + 8*w + 2*cl + m;
        float sc = (g == 2) ? 2.f*LOG2E : LOG2E;
        int k = 32*kt + (lane>>4)*8 + b;
        W2F[idx] = (_Float16)(((k < 64) ? W_ih2[row*64 + k] : W_hh2[row*64 + (k-64)]) * sc);
    }
    // W3F: [w:4][kt:2][lane][b] — GAT projection (unscaled, used by waves 0-3)
    for (int idx = tid; idx < 4096; idx += nth){
        int b = idx & 7, t1 = idx >> 3; int lane = t1 & 63, t2 = t1 >> 6;
        int kt = t2 & 1, w = t2 >> 1;
        int row = 16*w + (lane & 15);
        W3F[idx] = (_Float16)glw[row*64 + 32*kt + (lane>>4)*8 + b];
    }
    // b2P: [w:8][m:2][lane][r:4] — layer2 bias, C-frag layout (gate r of ch 8w+2grp+m)
    for (int idx = tid; idx < 4096; idx += nth){
        int r = idx & 3;
        int lane = (idx >> 2) & 63;
        int m = (idx >> 8) & 1;
        int w = idx >> 9;           // 0..7
        int grp = lane >> 4;
        int row = r*64 + 8*w + 2*grp + m;
        float sc = (r == 2) ? 2.f*LOG2E : LOG2E;
        b2P[idx] = (b_ih2[row] + b_hh2[row]) * sc;
    }
    if (tid < 4){ float s = 0.f; for (int c = 0; c < 16; c++) s += atte[tid*16+c]*glew[tid*16+c]; ke[tid] = s; }
    if (tid == 0){ int nz = 0;
        for (int i = 0; i < 4096; i++){ if ((i&3) != 0 && mask_bytes[i] != 0) nz++; }
        *flag = (nz == 0) ? 1 : 0; }
}

// ---------------- CSR build: degree count ----------------
__global__ __launch_bounds__(256) void count_kernel(
    const int* __restrict__ ei, const void* __restrict__ maskp, const int* __restrict__ flag,
    int* __restrict__ deg, int E)
{
    int e = blockIdx.x*256 + threadIdx.x;
    if (e >= E) return;
    bool m = (*flag) ? (((const int*)maskp)[e] != 0) : (((const unsigned char*)maskp)[e] != 0);
    if (!m) return;
    atomicAdd(deg + ei[E + e], 1);
}

// ---------------- CSR build: single-block exclusive scan, int4 ----------------
__global__ __launch_bounds__(1024) void scan_kernel(
    const int* __restrict__ deg, int* __restrict__ offs, int* __restrict__ cursor, int nn)
{
    __shared__ int wsum[16];
    __shared__ int sbase;
    int lane = threadIdx.x & 63, wv = threadIdx.x >> 6;
    if (threadIdx.x == 0) sbase = 0;
    __syncthreads();
    for (int base = 0; base < nn; base += 4096){
        int i0 = base + (int)threadIdx.x*4;
        int4 v = make_int4(0,0,0,0);
        if (i0 + 3 < nn) v = *(const int4*)(deg + i0);
        else {
            if (i0   < nn) v.x = deg[i0];
            if (i0+1 < nn) v.y = deg[i0+1];
            if (i0+2 < nn) v.z = deg[i0+2];
            if (i0+3 < nn) v.w = deg[i0+3];
        }
        int s = v.x + v.y + v.z + v.w;
        int sc = s;
        #pragma unroll
        for (int o = 1; o < 64; o <<= 1){ int t = __shfl_up(sc, o); if (lane >= o) sc += t; }
        if (lane == 63) wsum[wv] = sc;
        __syncthreads();
        int wbase = 0, total = 0;
        #pragma unroll
        for (int k = 0; k < 16; k++){ int sk = wsum[k]; if (k < wv) wbase += sk; total += sk; }
        int excl = sbase + wbase + sc - s;
        if (i0 < nn){
            int e0 = excl, e1 = e0 + v.x, e2 = e1 + v.y, e3 = e2 + v.z;
            if (i0 + 3 < nn){
                *(int4*)(offs + i0)   = make_int4(e0,e1,e2,e3);
                *(int4*)(cursor + i0) = make_int4(e0,e1,e2,e3);
            } else {
                offs[i0] = e0; cursor[i0] = e0;
                if (i0+1 < nn){ offs[i0+1] = e1; cursor[i0+1] = e1; }
                if (i0+2 < nn){ offs[i0+2] = e2; cursor[i0+2] = e2; }
            }
        }
        __syncthreads();
        if (threadIdx.x == 0) sbase += total;
        __syncthreads();
    }
    if (threadIdx.x == 0) offs[nn] = sbase;
}

// ---------------- CSR build: scatter (src, edge_attr) records ----------------
__global__ __launch_bounds__(256) void scatter_kernel(
    const int* __restrict__ ei, const float* __restrict__ ea, const void* __restrict__ maskp,
    const int* __restrict__ flag, int* __restrict__ cursor, int2* __restrict__ rec, int E)
{
    int e = blockIdx.x*256 + threadIdx.x;
    if (e >= E) return;
    bool m = (*flag) ? (((const int*)maskp)[e] != 0) : (((const unsigned char*)maskp)[e] != 0);
    if (!m) return;
    int d = ei[E + e];
    int pos = atomicAdd(cursor + d, 1);
    rec[pos] = make_int2(ei[e], __float_as_int(ea[e]));
}

// ---------------- one LSTM time-step (8-wave / 32-node, half2 stores, 2 barriers) ----------------
__device__ __forceinline__ void lstm_step(
    const _Float16* RB, _Float16* WB, const _Float16* x_lds, int t,
    const half8 (&w1f)[2][3], const half8 (&w2f)[2][4], const floatx4 (&b2v)[2],
    float* c1s, float* c2s, int col, int grp, int wv)
{
    // ---- layer 1: reads RB.h1, writes WB.h1 ----
    #pragma unroll
    for (int nt = 0; nt < 2; nt++){
        int node = nt*16 + col;
        half8 bf0 = *(const half8*)&RB[node*PITCH2 + grp*8];
        half8 bf1 = *(const half8*)&RB[node*PITCH2 + 32 + grp*8];
        half8 xb;
        #pragma unroll
        for (int b = 0; b < 8; b++) xb[b] = (_Float16)0.f;
        _Float16 xv = x_lds[node*26 + t];
        if (grp == 0){ xb[0] = xv; xb[1] = (_Float16)1.0f; }
        floatx4 aA = {0,0,0,0}, aB = {0,0,0,0};
        aA = MFMA16(w1f[0][0], bf0, aA);  aB = MFMA16(w1f[1][0], bf0, aB);
        aA = MFMA16(w1f[0][1], bf1, aA);  aB = MFMA16(w1f[1][1], bf1, aB);
        aA = MFMA16(w1f[0][2], xb,  aA);  aB = MFMA16(w1f[1][2], xb,  aB);
        _Float16 hA, hB;
        ACT(aA[0], aA[1], aA[2], aA[3], c1s[nt*2+0], hA);
        ACT(aB[0], aB[1], aB[2], aB[3], c1s[nt*2+1], hB);
        half2_t hh; hh[0] = hA; hh[1] = hB;
        *(half2_t*)&WB[node*PITCH2 + 8*wv + 2*grp] = hh;   // channels 8w+2grp, +1
    }
    __syncthreads();
    // ---- layer 2: reads WB.h1 + RB.h2, writes WB.h2 ----
    #pragma unroll
    for (int nt = 0; nt < 2; nt++){
        int node = nt*16 + col;
        half8 bf0 = *(const half8*)&WB[node*PITCH2 + grp*8];
        half8 bf1 = *(const half8*)&WB[node*PITCH2 + 32 + grp*8];
        half8 bf2 = *(const half8*)&RB[node*PITCH2 + 64 + grp*8];
        half8 bf3 = *(const half8*)&RB[node*PITCH2 + 96 + grp*8];
        floatx4 aA = b2v[0], aB = b2v[1];
        aA = MFMA16(w2f[0][0], bf0, aA);  aB = MFMA16(w2f[1][0], bf0, aB);
        aA = MFMA16(w2f[0][1], bf1, aA);  aB = MFMA16(w2f[1][1], bf1, aB);
        aA = MFMA16(w2f[0][2], bf2, aA);  aB = MFMA16(w2f[1][2], bf2, aB);
        aA = MFMA16(w2f[0][3], bf3, aA);  aB = MFMA16(w2f[1][3], bf3, aB);
        _Float16 hA, hB;
        ACT(aA[0], aA[1], aA[2], aA[3], c2s[nt*2+0], hA);
        ACT(aB[0], aB[1], aB[2], aB[3], c2s[nt*2+1], hB);
        half2_t hh; hh[0] = hA; hh[1] = hB;
        *(half2_t*)&WB[node*PITCH2 + 64 + 8*wv + 2*grp] = hh;
    }
    __syncthreads();
}

// ---------------- fused MFMA LSTM + GAT projection + attention dots ----------------
// 8 waves x 32 nodes, VGPR 60 — PINNED under the 64-VGPR occupancy cliff
// (R13 lesson: +8 VGPR -> waves/SIMD halve -> +27% time). Do not add live state.
__global__ __launch_bounds__(512) void lstm_kernel(
    const float* __restrict__ x_in,
    const _Float16* __restrict__ W1F, const _Float16* __restrict__ W2F, const _Float16* __restrict__ W3F,
    const float* __restrict__ b2P,
    const float* __restrict__ atts, const float* __restrict__ attd,
    float* __restrict__ x_out, float* __restrict__ a_src, float* __restrict__ a_dst, int nn)
{
    __shared__ _Float16 hbuf0[32*PITCH2];
    __shared__ _Float16 hbuf1[32*PITCH2];
    __shared__ _Float16 x_lds[32*26];

    const int wv   = threadIdx.x >> 6;     // 0..7
    const int lane = threadIdx.x & 63;
    const int grp  = lane >> 4;
    const int col  = lane & 15;
    const int node0 = blockIdx.x * 32;

    for (int i = threadIdx.x; i < 32*T_STEPS; i += 512){
        int node = i / T_STEPS, t = i % T_STEPS;
        int nd = node0 + node;
        x_lds[node*26 + t] = (_Float16)((nd < nn) ? x_in[nd*T_STEPS + t] : 0.f);
    }
    for (int i = threadIdx.x; i < 32*PITCH2/2; i += 512) ((float*)hbuf0)[i] = 0.f;

    const half8* W1Fv = (const half8*)W1F;
    const half8* W2Fv = (const half8*)W2F;
    half8 w1f[2][3], w2f[2][4];
    floatx4 b2v[2];
    #pragma unroll
    for (int m = 0; m < 2; m++){
        #pragma unroll
        for (int kt = 0; kt < 3; kt++) w1f[m][kt] = W1Fv[((wv*2+m)*3+kt)*64 + lane];
        #pragma unroll
        for (int kt = 0; kt < 4; kt++) w2f[m][kt] = W2Fv[((wv*2+m)*4+kt)*64 + lane];
        b2v[m] = *(const floatx4*)&b2P[((wv*2+m)*64 + lane)*4];
    }

    float c1s[4], c2s[4];
    #pragma unroll
    for (int i = 0; i < 4; i++){ c1s[i] = 0.f; c2s[i] = 0.f; }

    __syncthreads();

    for (int t = 0; t < T_STEPS; t += 2){
        lstm_step(hbuf0, hbuf1, x_lds, t,   w1f, w2f, b2v, c1s, c2s, col, grp, wv);
        lstm_step(hbuf1, hbuf0, x_lds, t+1, w1f, w2f, b2v, c1s, c2s, col, grp, wv);
    }
    // final h2 in hbuf0

    // ---------- GAT projection + attention dots (waves 0-3 only; wave w = head w) ----------
    if (wv < 4){
        const half8* W3Fv = (const half8*)W3F;
        half8 w3f0 = W3Fv[(wv*2+0)*64 + lane];
        half8 w3f1 = W3Fv[(wv*2+1)*64 + lane];
        float asw[4], adw[4];
        #pragma unroll
        for (int r = 0; r < 4; r++){ int ch = 16*wv + grp*4 + r; asw[r] = atts[ch]; adw[r] = attd[ch]; }
        #pragma unroll
        for (int nt = 0; nt < 2; nt++){
            int node = nt*16 + col;
            int nd = node0 + node;
            floatx4 pa = {0,0,0,0};
            half8 bf0 = *(const half8*)&hbuf0[node*PITCH2 + 64 + grp*8];
            half8 bf1 = *(const half8*)&hbuf0[node*PITCH2 + 96 + grp*8];
            pa = MFMA16(w3f0, bf0, pa);
            pa = MFMA16(w3f1, bf1, pa);
            float s  = pa[0]*asw[0] + pa[1]*asw[1] + pa[2]*asw[2] + pa[3]*asw[3];
            float dv = pa[0]*adw[0] + pa[1]*adw[1] + pa[2]*adw[2] + pa[3]*adw[3];
            s  += __shfl_xor(s, 16);  s  += __shfl_xor(s, 32);
            dv += __shfl_xor(dv, 16); dv += __shfl_xor(dv, 32);
            if (nd < nn){
                *(float4*)(x_out + (size_t)nd*64 + 16*wv + grp*4) = make_float4(pa[0], pa[1], pa[2], pa[3]);
                if (grp == 0) a_src[nd*4 + wv] = s;
                else if (grp == 1) a_dst[nd*4 + wv] = dv;
            }
        }
    }
}

// ---------------- gather: wave-per-node CSR aggregation + fused finalize (4-way unroll) ----------------
__global__ __launch_bounds__(256) void gather_kernel(
    const int2* __restrict__ rec, const int* __restrict__ offs,
    const float* __restrict__ a_src, const float* __restrict__ a_dst, const float* __restrict__ ke,
    const float* __restrict__ xf, const float* __restrict__ gbias,
    const float* __restrict__ fcw, const float* __restrict__ fcb,
    float* __restrict__ y, int nn)
{
    int wv = threadIdx.x >> 6, lane = threadIdx.x & 63;
    int node = blockIdx.x*4 + wv;
    if (node >= nn) return;
    int h = lane >> 4;
    float keh = ke[h];
    float adv = a_dst[4*node + h];
    int beg = offs[node], end = offs[node+1];
    float acc = 0.f, dacc = 0.f;
    int j = beg;
    for (; j + 3 < end; j += 4){
        int2 r0 = rec[j], r1 = rec[j+1], r2 = rec[j+2], r3 = rec[j+3];
        int s0 = r0.x, s1 = r1.x, s2 = r2.x, s3 = r3.x;
        float as0 = a_src[4*s0 + h], as1 = a_src[4*s1 + h];
        float as2 = a_src[4*s2 + h], as3 = a_src[4*s3 + h];
        float x0 = xf[(size_t)s0*64 + lane], x1 = xf[(size_t)s1*64 + lane];
        float x2 = xf[(size_t)s2*64 + lane], x3 = xf[(size_t)s3*64 + lane];
        float a0 = as0 + adv + __int_as_float(r0.y)*keh;
        float a1 = as1 + adv + __int_as_float(r1.y)*keh;
        float a2 = as2 + adv + __int_as_float(r2.y)*keh;
        float a3 = as3 + adv + __int_as_float(r3.y)*keh;
        a0 = a0 > 0.f ? a0 : NSLOPE*a0;
        a1 = a1 > 0.f ? a1 : NSLOPE*a1;
        a2 = a2 > 0.f ? a2 : NSLOPE*a2;
        a3 = a3 > 0.f ? a3 : NSLOPE*a3;
        float e0 = __expf(a0), e1 = __expf(a1), e2 = __expf(a2), e3 = __expf(a3);
        dacc += (e0 + e1) + (e2 + e3);
        acc = fmaf(e0, x0, acc);
        acc = fmaf(e1, x1, acc);
        acc = fmaf(e2, x2, acc);
        acc = fmaf(e3, x3, acc);
    }
    for (; j < end; ++j){
        int2 r = rec[j];
        int s = r.x;
        float a = a_src[4*s + h] + adv + __int_as_float(r.y)*keh;
        a = a > 0.f ? a : NSLOPE*a;
        float ev = __expf(a);
        dacc += ev;
        acc = fmaf(ev, xf[(size_t)s*64 + lane], acc);
    }
    float v = acc * RCP(fmaxf(dacc, 1e-16f)) + gbias[lane];
    v = v > 0.f ? v : (__expf(v) - 1.f);
    float r2 = v * fcw[lane];
    #pragma unroll
    for (int off = 1; off < 64; off <<= 1) r2 += __shfl_xor(r2, off, 64);
    if (lane == 0) y[node] = r2 + fcb[0];
}

extern "C" void kernel_launch(void* const* d_in, const int* in_sizes, int n_in,
                              void* d_out, int out_size, void* d_ws, size_t ws_size,
                              hipStream_t stream)
{
    const float* x_in  = (const float*)d_in[0];
    const int*   ei    = (const int*)d_in[1];
    const float* ea    = (const float*)d_in[2];
    const void*  mask  = d_in[3];
    const float* W_ih1 = (const float*)d_in[4];
    const float* W_hh1 = (const float*)d_in[5];
    const float* b_ih1 = (const float*)d_in[6];
    const float* b_hh1 = (const float*)d_in[7];
    const float* W_ih2 = (const float*)d_in[8];
    const float* W_hh2 = (const float*)d_in[9];
    const float* b_ih2 = (const float*)d_in[10];
    const float* b_hh2 = (const float*)d_in[11];
    const float* glw   = (const float*)d_in[12];
    const float* glew  = (const float*)d_in[13];
    const float* atts  = (const float*)d_in[14];
    const float* attd  = (const float*)d_in[15];
    const float* atte  = (const float*)d_in[16];
    const float* gbias = (const float*)d_in[17];
    const float* fcw   = (const float*)d_in[18];
    const float* fcb   = (const float*)d_in[19];

    const int NN = in_sizes[0] / T_STEPS;
    const int E  = in_sizes[1] / 2;

    float* ws = (float*)d_ws;
    size_t o = 0;
    _Float16* W1F = (_Float16*)(ws + o); o += 24576/2;
    _Float16* W2F = (_Float16*)(ws + o); o += 32768/2;
    _Float16* W3F = (_Float16*)(ws + o); o += 4096/2;
    float* b2P = ws + o; o += 4096;
    float* ke  = ws + o; o += 64;
    int*  flag = (int*)(ws + o); o += 64;
    float* asrc= ws + o; o += (size_t)NN*4;
    float* adst= ws + o; o += (size_t)NN*4;
    float* xf  = ws + o; o += (size_t)NN*64;
    int* deg    = (int*)(ws + o); o += NN;
    int* offs   = (int*)(ws + o); o += NN + 64;
    int* cursor = (int*)(ws + o); o += NN;
    int2* rec   = (int2*)(ws + o); o += (size_t)E*2;

    prep_kernel<<<128, 256, 0, stream>>>(W_ih1, W_hh1, b_ih1, b_hh1, W_ih2, W_hh2, b_ih2, b_hh2,
                                         glw, glew, atte, (const unsigned char*)mask,
                                         W1F, W2F, W3F, b2P, ke, flag, deg, NN);
    count_kernel<<<(E + 255)/256, 256, 0, stream>>>(ei, mask, flag, deg, E);
    scan_kernel<<<1, 1024, 0, stream>>>(deg, offs, cursor, NN);
    scatter_kernel<<<(E + 255)/256, 256, 0, stream>>>(ei, ea, mask, flag, cursor, rec, E);
    lstm_kernel<<<(NN + 31)/32, 512, 0, stream>>>(x_in, W1F, W2F, W3F, b2P,
                                                  atts, attd, xf, asrc, adst, NN);
    gather_kernel<<<(NN + 3)/4, 256, 0, stream>>>(rec, offs, asrc, adst, ke, xf,
                                                  gbias, fcw, fcb, (float*)d_out, NN);
}